// Round 15
// baseline (84.703 us; speedup 1.0000x reference)
//
#include <hip/hip_runtime.h>
#include <hip/hip_bf16.h>
#include <stdint.h>

typedef __attribute__((ext_vector_type(8))) short short8;
typedef __attribute__((ext_vector_type(4))) float f32x4;
typedef __attribute__((ext_vector_type(16))) float f32x16;
typedef __attribute__((ext_vector_type(4))) int i32x4;
typedef __attribute__((ext_vector_type(8))) int i32x8;

#define N_PTS 8192
#define M_PTS 8192
#define DIM   512
#define KDIM  128
#define BT    128   // phi_b tile
#define BKS   32

// ---- float <-> order-preserving uint key (for atomicMin on float) ----
__device__ __forceinline__ unsigned fenc(float f) {
  unsigned u = __float_as_uint(f);
  return (u & 0x80000000u) ? ~u : (u | 0x80000000u);
}
__device__ __forceinline__ float fdec(unsigned k) {
  unsigned u = (k & 0x80000000u) ? (k ^ 0x80000000u) : ~k;
  return __uint_as_float(u);
}

__device__ __forceinline__ unsigned short f2bf(float f) {
  union { __hip_bfloat16 h; unsigned short u; } c;
  c.h = __float2bfloat16(f);
  return c.u;
}

// ---- float -> OCP e4m3fn, RNE, flush |f|<2^-6 to 0 (x,t ~ N(0,1)) ----
__device__ __forceinline__ unsigned f2e4m3(float f) {
  unsigned u = __float_as_uint(f);
  unsigned s = (u >> 24) & 0x80;
  unsigned mag = u & 0x7fffffffu;
  unsigned r = mag + 0x0007ffffu + ((mag >> 20) & 1u);  // RNE to 3 mantissa bits
  int e = (int)(r >> 23) - 127;
  if (e < -6) return s;                                 // flush tiny to zero
  unsigned m = (r >> 20) & 7u;
  return s | (unsigned)((e + 7) << 3) | m;
}

// ---- async global -> LDS, 16B per lane (phi_b kernel only) ----
__device__ __forceinline__ void async_copy16(const void* g, void* l) {
  __builtin_amdgcn_global_load_lds(
      (const __attribute__((address_space(1))) void*)g,
      (__attribute__((address_space(3))) void*)l, 16, 0, 0);
}

// ---- bf16 LDS slot swizzle (phi_b kernel, verified 0 conflicts) ----
__device__ __forceinline__ int swz_slot(int row, int slot) {
  return slot ^ ((row >> 1) & 3);
}

// =====================================================================
// Kernel 1: prep-all. Blocks < 4096: one wave per row of x/target:
// x -> Xb(bf16) + XfT(e4m3 FRAGMENT-MAJOR [kt][8192][64B]) + xsq;
// target -> TfT (same frag-major) + tsq + key init.
// Blocks >= 4096: W [D][K] fp32 -> WbT [K][D] bf16 transpose-cast.
// =====================================================================
__global__ __launch_bounds__(256)
void prep_all_kernel(const float* __restrict__ x, const float* __restrict__ tgt,
                     const float* __restrict__ W,
                     unsigned short* __restrict__ Xb, unsigned char* __restrict__ XfT,
                     unsigned char* __restrict__ TfT, unsigned short* __restrict__ WbT,
                     float* __restrict__ xsq, float* __restrict__ tsq,
                     unsigned* __restrict__ keys) {
  const int bid = blockIdx.x;
  const int tid = threadIdx.x;
  if (bid >= (N_PTS + M_PTS) / 4) {
    const int o = (bid - (N_PTS + M_PTS) / 4) * 256 + tid;  // 0..65535
    const int k = o >> 9, d = o & 511;
    WbT[o] = f2bf(W[d * KDIM + k]);
    return;
  }
  const int gw = (bid * 256 + tid) >> 6;
  const int j = tid & 63;
  float s;
  if (gw < N_PTS) {
    const float* src = x + (size_t)gw * DIM + j * 8;
    float4 v0 = *(const float4*)src;
    float4 v1 = *(const float4*)(src + 4);
    s = v0.x * v0.x + v0.y * v0.y + v0.z * v0.z + v0.w * v0.w +
        v1.x * v1.x + v1.y * v1.y + v1.z * v1.z + v1.w * v1.w;
    unsigned short* db = Xb + (size_t)gw * DIM + j * 8;
    ushort4 ob0, ob1;
    ob0.x = f2bf(v0.x); ob0.y = f2bf(v0.y); ob0.z = f2bf(v0.z); ob0.w = f2bf(v0.w);
    ob1.x = f2bf(v1.x); ob1.y = f2bf(v1.y); ob1.z = f2bf(v1.z); ob1.w = f2bf(v1.w);
    *(ushort4*)db = ob0;
    *(ushort4*)(db + 4) = ob1;
    unsigned long long p = (unsigned long long)f2e4m3(v0.x)
        | ((unsigned long long)f2e4m3(v0.y) << 8)
        | ((unsigned long long)f2e4m3(v0.z) << 16)
        | ((unsigned long long)f2e4m3(v0.w) << 24)
        | ((unsigned long long)f2e4m3(v1.x) << 32)
        | ((unsigned long long)f2e4m3(v1.y) << 40)
        | ((unsigned long long)f2e4m3(v1.z) << 48)
        | ((unsigned long long)f2e4m3(v1.w) << 56);
    // fragment-major: [kt = j>>3][row gw][byte (j&7)*8]
    *(unsigned long long*)(XfT + ((size_t)(j >> 3) * N_PTS + gw) * 64 + (j & 7) * 8) = p;
#pragma unroll
    for (int m = 1; m <= 32; m <<= 1) s += __shfl_xor(s, m);
    if (j == 0) xsq[gw] = s;
  } else {
    const int tr = gw - N_PTS;
    const float* src = tgt + (size_t)tr * DIM + j * 8;
    float4 v0 = *(const float4*)src;
    float4 v1 = *(const float4*)(src + 4);
    s = v0.x * v0.x + v0.y * v0.y + v0.z * v0.z + v0.w * v0.w +
        v1.x * v1.x + v1.y * v1.y + v1.z * v1.z + v1.w * v1.w;
    unsigned long long p = (unsigned long long)f2e4m3(v0.x)
        | ((unsigned long long)f2e4m3(v0.y) << 8)
        | ((unsigned long long)f2e4m3(v0.z) << 16)
        | ((unsigned long long)f2e4m3(v0.w) << 24)
        | ((unsigned long long)f2e4m3(v1.x) << 32)
        | ((unsigned long long)f2e4m3(v1.y) << 40)
        | ((unsigned long long)f2e4m3(v1.z) << 48)
        | ((unsigned long long)f2e4m3(v1.w) << 56);
    *(unsigned long long*)(TfT + ((size_t)(j >> 3) * M_PTS + tr) * 64 + (j & 7) * 8) = p;
#pragma unroll
    for (int m = 1; m <= 32; m <<= 1) s += __shfl_xor(s, m);
    if (j == 0) { tsq[tr] = s; keys[tr] = 0xFFFFFFFFu; }
  }
}

// =====================================================================
// Kernel 2: phi_b = logsumexp(Xb @ WbT^T) via bf16 MFMA (unchanged).
// =====================================================================
__global__ __launch_bounds__(256)
void phi_b_kernel(const short* __restrict__ Xb, const short* __restrict__ WbT,
                  float* __restrict__ phi_b) {
  __shared__ __align__(16) short As[BT * BKS];
  __shared__ __align__(16) short Bs[BT * BKS];
  __shared__ __align__(16) float lg[128][136];

  const int tid = threadIdx.x;
  const int wave = tid >> 6, lane = tid & 63;
  const int n0 = blockIdx.x * BT;
  const int srow = tid >> 2;
  const int sk8 = swz_slot(srow, tid & 3) * 8;
  const int wr = wave >> 1, wc = wave & 1;
  const int fr = lane & 15, g = lane >> 4;

  f32x4 acc[4][4] = {};
  for (int kt = 0; kt < DIM / BKS; ++kt) {
    const int k0 = kt * BKS;
    async_copy16(Xb + (size_t)(n0 + srow) * DIM + k0 + sk8, &As[wave * 512]);
    async_copy16(Xb + (size_t)(n0 + srow + 64) * DIM + k0 + sk8, &As[2048 + wave * 512]);
    async_copy16(WbT + (size_t)srow * DIM + k0 + sk8, &Bs[wave * 512]);
    async_copy16(WbT + (size_t)(srow + 64) * DIM + k0 + sk8, &Bs[2048 + wave * 512]);
    __syncthreads();
    short8 a[4], b[4];
#pragma unroll
    for (int i = 0; i < 4; ++i) {
      const int R = wr * 64 + i * 16 + fr;
      a[i] = *(const short8*)&As[R * BKS + swz_slot(R, g) * 8];
    }
#pragma unroll
    for (int j = 0; j < 4; ++j) {
      const int R = wc * 64 + j * 16 + fr;
      b[j] = *(const short8*)&Bs[R * BKS + swz_slot(R, g) * 8];
    }
#pragma unroll
    for (int i = 0; i < 4; ++i)
#pragma unroll
      for (int j = 0; j < 4; ++j)
        acc[i][j] = __builtin_amdgcn_mfma_f32_16x16x32_bf16(a[i], b[j], acc[i][j], 0, 0, 0);
    __syncthreads();
  }

  const int rq = g * 4;
#pragma unroll
  for (int i = 0; i < 4; ++i)
#pragma unroll
    for (int j = 0; j < 4; ++j)
#pragma unroll
      for (int q = 0; q < 4; ++q)
        lg[wr * 64 + i * 16 + rq + q][wc * 64 + j * 16 + fr] = acc[i][j][q];
  __syncthreads();

  const int row = tid >> 1, half = tid & 1;
  const float4* lr = (const float4*)(&lg[row][half * 64]);
  float mx = -3.4e38f;
#pragma unroll
  for (int c = 0; c < 16; ++c) {
    float4 v = lr[c];
    mx = fmaxf(mx, fmaxf(fmaxf(v.x, v.y), fmaxf(v.z, v.w)));
  }
  mx = fmaxf(mx, __shfl_xor(mx, 1));
  float s = 0.f;
#pragma unroll
  for (int c = 0; c < 16; ++c) {
    float4 v = lr[c];
    s += __expf(v.x - mx) + __expf(v.y - mx) + __expf(v.z - mx) + __expf(v.w - mx);
  }
  s += __shfl_xor(s, 1);
  if (half == 0) phi_b[n0 + row] = mx + logf(s);
}

// =====================================================================
// Kernel 3: fused MX-fp8 GEMM + min epilogue — ALL-REGISTER, NO LDS,
// NO BARRIERS. 256x256 tile, 8 waves (4wm x 2wn), wave = 64n x 128m
// (acc 2x4 f32x16 = 128 regs). Both operands fragment-major in L2
// (XfT/TfT [kt][8192][64B]); each wave loads its fragments directly
// to registers (2 x dwordx4 per frag). K-loop fully unrolled; the
// compiler software-pipelines loads across tiles with counted vmcnt.
// Waves are fully independent -> no convoy, no races.
// =====================================================================
__device__ __forceinline__ i32x8 ld2x16(const unsigned char* p0, const unsigned char* p1) {
  i32x4 lo = *(const i32x4*)p0;
  i32x4 hi = *(const i32x4*)p1;
  return __builtin_shufflevector(lo, hi, 0, 1, 2, 3, 4, 5, 6, 7);
}

__device__ __forceinline__ f32x16 mfma_mx(i32x8 a, i32x8 b, f32x16 c) {
  return __builtin_amdgcn_mfma_scale_f32_32x32x64_f8f6f4(a, b, c, 0, 0,
                                                         0, 0x7F, 0, 0x7F);
}

__global__ __launch_bounds__(512, 2)
void gemm_min_kernel(const unsigned char* __restrict__ XfT, const unsigned char* __restrict__ TfT,
                     const float* __restrict__ phi_b, unsigned* __restrict__ keys) {
  const int tid = threadIdx.x;
  const int wave = tid >> 6, lane = tid & 63;
  const int wm = wave >> 1, wn = wave & 1;   // 4 x 2
  const int fr5 = lane & 31, h = lane >> 5;

  // 2D XCD chunking: 8 chunks of 8n x 16m 256-tiles (~3MB / XCD L2)
  const int bid = blockIdx.x;                 // 0..1023
  const int xcd = bid & 7, idx = bid >> 3;    // idx 0..127
  const int nt = (xcd >> 1) * 8 + (idx >> 4); // 0..31
  const int mt = (xcd & 1) * 16 + (idx & 15); // 0..31
  const int n0 = nt * 256, m0 = mt * 256;

  // fragment bases (fragment-major [kt][row][64]): lane reads bytes h*32..+31
  const unsigned char* Ab = XfT + ((size_t)(n0 + wm * 64 + fr5)) * 64 + h * 32;
  const unsigned char* Bb = TfT + ((size_t)(m0 + wn * 128 + fr5)) * 64 + h * 32;
  const size_t KT = (size_t)N_PTS * 64;       // 524288 bytes per kt plane

  f32x16 acc[2][4] = {};
#pragma unroll
  for (int kt = 0; kt < 8; ++kt) {
    i32x8 fa[2], fb[4];
#pragma unroll
    for (int i = 0; i < 2; ++i) {
      const unsigned char* p = Ab + kt * KT + i * 2048;
      fa[i] = ld2x16(p, p + 16);
    }
#pragma unroll
    for (int j = 0; j < 4; ++j) {
      const unsigned char* p = Bb + kt * KT + j * 2048;
      fb[j] = ld2x16(p, p + 16);
    }
#pragma unroll
    for (int i = 0; i < 2; ++i)
#pragma unroll
      for (int j = 0; j < 4; ++j)
        acc[i][j] = mfma_mx(fa[i], fb[j], acc[i][j]);
  }

  // Epilogue: v = phi_b[n] - dot; min over this wave's 64 n-rows.
  // 32x32 C/D layout (m74/m101): col = lane&31 (m-frag row),
  // n-row-in-frag = (q&3)+8*(q>>2)+4*h.
  float pb[2][16];
#pragma unroll
  for (int i = 0; i < 2; ++i)
#pragma unroll
    for (int q = 0; q < 16; ++q)
      pb[i][q] = phi_b[n0 + wm * 64 + i * 32 + (q & 3) + 8 * (q >> 2) + 4 * h];

  float mv[4] = {3.4e38f, 3.4e38f, 3.4e38f, 3.4e38f};
#pragma unroll
  for (int i = 0; i < 2; ++i)
#pragma unroll
    for (int j = 0; j < 4; ++j)
#pragma unroll
      for (int q = 0; q < 16; ++q)
        mv[j] = fminf(mv[j], pb[i][q] - acc[i][j][q]);
#pragma unroll
  for (int j = 0; j < 4; ++j) {
    float v = fminf(mv[j], __shfl_xor(mv[j], 32));
    if (h == 0) atomicMin(&keys[m0 + wn * 128 + j * 32 + fr5], fenc(v));
  }
}

// =====================================================================
// Kernel 4: partial reduce — 64 blocks x 256 threads (unchanged r12).
// =====================================================================
__global__ __launch_bounds__(256)
void partial_kernel(const float* __restrict__ xsq, const float* __restrict__ phi_b,
                    const float* __restrict__ tsq, const unsigned* __restrict__ keys,
                    double* __restrict__ partials) {
  const int b = blockIdx.x, t = threadIdx.x;
  double s;
  if (b < 32) {
    const int n = b * 256 + t;
    s = 0.5 * (double)xsq[n] - (double)phi_b[n];
  } else {
    const int m = (b - 32) * 256 + t;
    s = 0.5 * (double)tsq[m] + (double)fdec(keys[m]);
  }
  const int lane = t & 63, wv = t >> 6;
#pragma unroll
  for (int k = 1; k <= 32; k <<= 1) s += __shfl_xor(s, k);
  __shared__ double ps[4];
  if (lane == 0) ps[wv] = s;
  __syncthreads();
  if (t == 0) partials[b] = ps[0] + ps[1] + ps[2] + ps[3];
}

// =====================================================================
// Kernel 5: final: sum 64 partials (fixed order), write scalar.
// =====================================================================
__global__ __launch_bounds__(64)
void final_kernel(const double* __restrict__ partials, float* __restrict__ out) {
  if (threadIdx.x == 0) {
    double a = 0.0, c = 0.0;
#pragma unroll
    for (int i = 0; i < 32; ++i) a += partials[i];
#pragma unroll
    for (int i = 32; i < 64; ++i) c += partials[i];
    out[0] = (float)(a / N_PTS + c / M_PTS);
  }
}

// =====================================================================
extern "C" void kernel_launch(void* const* d_in, const int* in_sizes, int n_in,
                              void* d_out, int out_size, void* d_ws, size_t ws_size,
                              hipStream_t stream) {
  const float* x = (const float*)d_in[0];
  const float* tgt = (const float*)d_in[1];
  const float* W = (const float*)d_in[2];

  char* ws = (char*)d_ws;
  const size_t XB_BYTES = (size_t)N_PTS * DIM * 2;   // bf16 x (for phi_b)
  const size_t XF_BYTES = (size_t)N_PTS * DIM;       // fp8 x (fragment-major)
  const size_t TF_BYTES = (size_t)M_PTS * DIM;       // fp8 t (fragment-major)
  const size_t WT_BYTES = (size_t)KDIM * DIM * 2;
  unsigned short* Xb = (unsigned short*)ws;
  unsigned char* XfT = (unsigned char*)(ws + XB_BYTES);
  unsigned char* TfT = (unsigned char*)(ws + XB_BYTES + XF_BYTES);
  unsigned short* WbT = (unsigned short*)(ws + XB_BYTES + XF_BYTES + TF_BYTES);
  float* phi_b = (float*)(ws + XB_BYTES + XF_BYTES + TF_BYTES + WT_BYTES);
  float* xsq = phi_b + N_PTS;
  float* tsq = xsq + N_PTS;
  unsigned* keys = (unsigned*)(tsq + M_PTS);
  double* partials = (double*)(keys + M_PTS + 64);   // 8B-aligned region

  const int prep_blocks = (N_PTS + M_PTS) / 4 + (KDIM * DIM) / 256;
  prep_all_kernel<<<prep_blocks, 256, 0, stream>>>(x, tgt, W, Xb, XfT, TfT, WbT,
                                                   xsq, tsq, keys);
  phi_b_kernel<<<N_PTS / BT, 256, 0, stream>>>((const short*)Xb, (const short*)WbT, phi_b);
  gemm_min_kernel<<<(N_PTS / 256) * (M_PTS / 256), 512, 0, stream>>>(XfT, TfT, phi_b, keys);
  partial_kernel<<<64, 256, 0, stream>>>(xsq, phi_b, tsq, keys, partials);
  final_kernel<<<1, 64, 0, stream>>>(partials, (float*)d_out);
}

// Round 16
// 64.533 us; speedup vs baseline: 1.3126x; 1.3126x over previous
//
#include <hip/hip_runtime.h>
#include <hip/hip_bf16.h>
#include <stdint.h>

typedef __attribute__((ext_vector_type(8))) short short8;
typedef __attribute__((ext_vector_type(4))) float f32x4;
typedef __attribute__((ext_vector_type(16))) float f32x16;
typedef __attribute__((ext_vector_type(4))) int i32x4;
typedef __attribute__((ext_vector_type(8))) int i32x8;

#define N_PTS 8192
#define M_PTS 8192
#define DIM   512
#define KDIM  128

// ---- float <-> order-preserving uint key (for atomicMin on float) ----
__device__ __forceinline__ unsigned fenc(float f) {
  unsigned u = __float_as_uint(f);
  return (u & 0x80000000u) ? ~u : (u | 0x80000000u);
}
__device__ __forceinline__ float fdec(unsigned k) {
  unsigned u = (k & 0x80000000u) ? (k ^ 0x80000000u) : ~k;
  return __uint_as_float(u);
}

__device__ __forceinline__ unsigned short f2bf(float f) {
  union { __hip_bfloat16 h; unsigned short u; } c;
  c.h = __float2bfloat16(f);
  return c.u;
}

// ---- float -> OCP e4m3fn, RNE, flush |f|<2^-6 to 0 (x,t ~ N(0,1)) ----
__device__ __forceinline__ unsigned f2e4m3(float f) {
  unsigned u = __float_as_uint(f);
  unsigned s = (u >> 24) & 0x80;
  unsigned mag = u & 0x7fffffffu;
  unsigned r = mag + 0x0007ffffu + ((mag >> 20) & 1u);  // RNE to 3 mantissa bits
  int e = (int)(r >> 23) - 127;
  if (e < -6) return s;                                 // flush tiny to zero
  unsigned m = (r >> 20) & 7u;
  return s | (unsigned)((e + 7) << 3) | m;
}

// ---- async global -> LDS, 16B per lane ----
__device__ __forceinline__ void async_copy16(const void* g, void* l) {
  __builtin_amdgcn_global_load_lds(
      (const __attribute__((address_space(1))) void*)g,
      (__attribute__((address_space(3))) void*)l, 16, 0, 0);
}

// ---- bf16 LDS slot swizzle (proven 0-conflict geometry) ----
__device__ __forceinline__ int swz_slot(int row, int slot) {
  return slot ^ ((row >> 1) & 3);
}

// ---- A-tile chunk key (row bits 1..4; stage/read-consistent) ----
__device__ __forceinline__ int chunk_key(int row) {
  return ((row >> 1) & 3) ^ ((row >> 3) & 1) ^ (((row >> 4) & 1) << 1);
}

#define BARRIER __builtin_amdgcn_s_barrier()

// =====================================================================
// Kernel 1: prep-all (r12 form). Blocks < 4096: one wave per row:
// x -> Xb(bf16) + Xf8(e4m3 plain rows) + xsq; target -> TfT (e4m3,
// fragment-major [kt][8192][64B]) + tsq + key init.
// Blocks >= 4096: W [D][K] fp32 -> WbT [K][D] bf16 transpose-cast.
// =====================================================================
__global__ __launch_bounds__(256)
void prep_all_kernel(const float* __restrict__ x, const float* __restrict__ tgt,
                     const float* __restrict__ W,
                     unsigned short* __restrict__ Xb, unsigned char* __restrict__ Xf8,
                     unsigned char* __restrict__ TfT, unsigned short* __restrict__ WbT,
                     float* __restrict__ xsq, float* __restrict__ tsq,
                     unsigned* __restrict__ keys) {
  const int bid = blockIdx.x;
  const int tid = threadIdx.x;
  if (bid >= (N_PTS + M_PTS) / 4) {
    const int o = (bid - (N_PTS + M_PTS) / 4) * 256 + tid;  // 0..65535
    const int k = o >> 9, d = o & 511;
    WbT[o] = f2bf(W[d * KDIM + k]);
    return;
  }
  const int gw = (bid * 256 + tid) >> 6;
  const int j = tid & 63;
  float s;
  if (gw < N_PTS) {
    const float* src = x + (size_t)gw * DIM + j * 8;
    float4 v0 = *(const float4*)src;
    float4 v1 = *(const float4*)(src + 4);
    s = v0.x * v0.x + v0.y * v0.y + v0.z * v0.z + v0.w * v0.w +
        v1.x * v1.x + v1.y * v1.y + v1.z * v1.z + v1.w * v1.w;
    unsigned short* db = Xb + (size_t)gw * DIM + j * 8;
    ushort4 ob0, ob1;
    ob0.x = f2bf(v0.x); ob0.y = f2bf(v0.y); ob0.z = f2bf(v0.z); ob0.w = f2bf(v0.w);
    ob1.x = f2bf(v1.x); ob1.y = f2bf(v1.y); ob1.z = f2bf(v1.z); ob1.w = f2bf(v1.w);
    *(ushort4*)db = ob0;
    *(ushort4*)(db + 4) = ob1;
    unsigned long long p = (unsigned long long)f2e4m3(v0.x)
        | ((unsigned long long)f2e4m3(v0.y) << 8)
        | ((unsigned long long)f2e4m3(v0.z) << 16)
        | ((unsigned long long)f2e4m3(v0.w) << 24)
        | ((unsigned long long)f2e4m3(v1.x) << 32)
        | ((unsigned long long)f2e4m3(v1.y) << 40)
        | ((unsigned long long)f2e4m3(v1.z) << 48)
        | ((unsigned long long)f2e4m3(v1.w) << 56);
    *(unsigned long long*)(Xf8 + (size_t)gw * DIM + j * 8) = p;
#pragma unroll
    for (int m = 1; m <= 32; m <<= 1) s += __shfl_xor(s, m);
    if (j == 0) xsq[gw] = s;
  } else {
    const int tr = gw - N_PTS;
    const float* src = tgt + (size_t)tr * DIM + j * 8;
    float4 v0 = *(const float4*)src;
    float4 v1 = *(const float4*)(src + 4);
    s = v0.x * v0.x + v0.y * v0.y + v0.z * v0.z + v0.w * v0.w +
        v1.x * v1.x + v1.y * v1.y + v1.z * v1.z + v1.w * v1.w;
    unsigned long long p = (unsigned long long)f2e4m3(v0.x)
        | ((unsigned long long)f2e4m3(v0.y) << 8)
        | ((unsigned long long)f2e4m3(v0.z) << 16)
        | ((unsigned long long)f2e4m3(v0.w) << 24)
        | ((unsigned long long)f2e4m3(v1.x) << 32)
        | ((unsigned long long)f2e4m3(v1.y) << 40)
        | ((unsigned long long)f2e4m3(v1.z) << 48)
        | ((unsigned long long)f2e4m3(v1.w) << 56);
    // fragment-major: [kt = j>>3][row tr][byte (j&7)*8]
    *(unsigned long long*)(TfT + ((size_t)(j >> 3) * M_PTS + tr) * 64 + (j & 7) * 8) = p;
#pragma unroll
    for (int m = 1; m <= 32; m <<= 1) s += __shfl_xor(s, m);
    if (j == 0) { tsq[tr] = s; keys[tr] = 0xFFFFFFFFu; }
  }
}

// =====================================================================
// Kernel 2: phi_b = logsumexp(Xb @ WbT^T) — RETILED: 256 blocks x
// 32 rows (was 64 x 128; only 25% of CUs). 4 waves = 4 col-quadrants
// of 32 logits. Per K32 step: stage A 2KB (waves 0-1) + B 8KB (all,
// identical geometry to proven version); 4 MFMA/wave. 16 steps.
// Then in-LDS logsumexp, 8 threads/row.
// =====================================================================
__global__ __launch_bounds__(256)
void phi_b_kernel(const short* __restrict__ Xb, const short* __restrict__ WbT,
                  float* __restrict__ phi_b) {
  __shared__ __align__(16) short As[32 * 32];
  __shared__ __align__(16) short Bs[128 * 32];
  __shared__ __align__(16) float lg[32][136];

  const int tid = threadIdx.x;
  const int wave = tid >> 6, lane = tid & 63;
  const int n0 = blockIdx.x * 32;
  const int fr = lane & 15, g = lane >> 4;
  const int wc = wave;                      // col quadrant 0..3

  const int srow = tid >> 2;                // 0..63 (B staging rows)
  const int sk8 = swz_slot(srow, tid & 3) * 8;
  const int ra = tid >> 2;                  // A staging row (waves 0-1: 0..31)
  const int ska = swz_slot(ra, tid & 3) * 8;

  f32x4 acc[2][2] = {};
  for (int kt = 0; kt < 16; ++kt) {
    const int k0 = kt * 32;
    if (wave < 2)
      async_copy16(Xb + (size_t)(n0 + ra) * DIM + k0 + ska, &As[wave * 512]);
    async_copy16(WbT + (size_t)srow * DIM + k0 + sk8, &Bs[wave * 512]);
    async_copy16(WbT + (size_t)(srow + 64) * DIM + k0 + sk8, &Bs[2048 + wave * 512]);
    __syncthreads();
    short8 a[2], b[2];
#pragma unroll
    for (int i = 0; i < 2; ++i) {
      const int R = i * 16 + fr;
      a[i] = *(const short8*)&As[R * 32 + swz_slot(R, g) * 8];
    }
#pragma unroll
    for (int jx = 0; jx < 2; ++jx) {
      const int R = wc * 32 + jx * 16 + fr;
      b[jx] = *(const short8*)&Bs[R * 32 + swz_slot(R, g) * 8];
    }
#pragma unroll
    for (int i = 0; i < 2; ++i)
#pragma unroll
      for (int jx = 0; jx < 2; ++jx)
        acc[i][jx] = __builtin_amdgcn_mfma_f32_16x16x32_bf16(a[i], b[jx], acc[i][jx], 0, 0, 0);
    __syncthreads();
  }

  // scatter logits: C/D layout col = lane&15, row = (lane>>4)*4 + q
  const int rq = g * 4;
#pragma unroll
  for (int i = 0; i < 2; ++i)
#pragma unroll
    for (int jx = 0; jx < 2; ++jx)
#pragma unroll
      for (int q = 0; q < 4; ++q)
        lg[i * 16 + rq + q][wc * 32 + jx * 16 + fr] = acc[i][jx][q];
  __syncthreads();

  // per-row logsumexp: 8 threads/row, 16 cols each (shfl within wave)
  const int row = tid >> 3, c8 = tid & 7;
  const float4* lr = (const float4*)(&lg[row][c8 * 16]);
  float mx = -3.4e38f;
#pragma unroll
  for (int c = 0; c < 4; ++c) {
    float4 v = lr[c];
    mx = fmaxf(mx, fmaxf(fmaxf(v.x, v.y), fmaxf(v.z, v.w)));
  }
  mx = fmaxf(mx, __shfl_xor(mx, 1));
  mx = fmaxf(mx, __shfl_xor(mx, 2));
  mx = fmaxf(mx, __shfl_xor(mx, 4));
  float s = 0.f;
#pragma unroll
  for (int c = 0; c < 4; ++c) {
    float4 v = lr[c];
    s += __expf(v.x - mx) + __expf(v.y - mx) + __expf(v.z - mx) + __expf(v.w - mx);
  }
  s += __shfl_xor(s, 1);
  s += __shfl_xor(s, 2);
  s += __shfl_xor(s, 4);
  if (c8 == 0) phi_b[n0 + row] = mx + logf(s);
}

// =====================================================================
// Kernel 3: fused MX-fp8 GEMM + min epilogue — r12 winner, verbatim.
// 256x256, 8 waves (2Mx4N), B direct from fragment-major TfT (L2),
// A staged in 3x16KB LDS stage-2-ahead, 1 barrier/K64,
// vmcnt(6)/4/none ledger.
// =====================================================================
__device__ __forceinline__ void stgA(const unsigned char* __restrict__ mat,
                                     int rowbase, int kbyte,
                                     unsigned char* dst, int tid) {
  const int r = tid >> 2, d = tid & 3;
  async_copy16(mat + (size_t)(rowbase + r) * DIM + kbyte + ((d ^ chunk_key(r)) << 4),
               dst + (tid >> 6) * 1024);
}

__device__ __forceinline__ i32x8 ld2x16(const unsigned char* p0, const unsigned char* p1) {
  i32x4 lo = *(const i32x4*)p0;
  i32x4 hi = *(const i32x4*)p1;
  return __builtin_shufflevector(lo, hi, 0, 1, 2, 3, 4, 5, 6, 7);
}

__device__ __forceinline__ f32x16 mfma_mx(i32x8 a, i32x8 b, f32x16 c) {
  return __builtin_amdgcn_mfma_scale_f32_32x32x64_f8f6f4(a, b, c, 0, 0,
                                                         0, 0x7F, 0, 0x7F);
}

template <int VMC, bool STG, bool LDB, bool BAR>
__device__ __forceinline__ void ktile(const unsigned char* Abuf, unsigned char* Sbuf,
                                      const unsigned char* __restrict__ Xf,
                                      const unsigned char* __restrict__ Bnx,
                                      int n0, int kstage, int tid, int aoff,
                                      i32x8 (&fb)[2], i32x8 (&fbn)[2],
                                      f32x16 (&acc)[4][2]) {
  i32x8 fa[4];
#pragma unroll
  for (int i = 0; i < 4; ++i)
    fa[i] = ld2x16(Abuf + aoff + i * 2048, Abuf + ((aoff + i * 2048) ^ 16));
  if (LDB) {
    fbn[0] = ld2x16(Bnx, Bnx + 16);
    fbn[1] = ld2x16(Bnx + 2048, Bnx + 2048 + 16);
  }
  if (STG) {
    stgA(Xf, n0, kstage, Sbuf, tid);
    stgA(Xf, n0 + 128, kstage, Sbuf + 8192, tid);
  }
  __builtin_amdgcn_s_setprio(1);
#pragma unroll
  for (int i = 0; i < 4; ++i) acc[i][0] = mfma_mx(fa[i], fb[0], acc[i][0]);
#pragma unroll
  for (int i = 0; i < 4; ++i) acc[i][1] = mfma_mx(fa[i], fb[1], acc[i][1]);
  __builtin_amdgcn_s_setprio(0);
  if (VMC == 6) asm volatile("s_waitcnt vmcnt(6)" ::: "memory");
  else if (VMC == 4) asm volatile("s_waitcnt vmcnt(4)" ::: "memory");
  else if (VMC == 0) asm volatile("s_waitcnt vmcnt(0)" ::: "memory");
  if (BAR) BARRIER;
}

__global__ __launch_bounds__(512, 2)
void gemm_min_kernel(const unsigned char* __restrict__ Xf, const unsigned char* __restrict__ TfT,
                     const float* __restrict__ phi_b, unsigned* __restrict__ keys) {
  __shared__ __align__(16) unsigned char lds8[49152];   // 3 x 16KB A buffers

  const int tid = threadIdx.x;
  const int wave = tid >> 6, lane = tid & 63;
  const int wm = wave >> 2, wn = wave & 3;
  const int fr5 = lane & 31, h = lane >> 5;

  // 2D XCD chunking: 8 chunks of 8n x 16m tiles (~3MB working set / XCD L2)
  const int bid = blockIdx.x;
  const int xcd = bid & 7, idx = bid >> 3;
  const int nt = (xcd >> 1) * 8 + (idx >> 4);
  const int mt = (xcd & 1) * 16 + (idx & 15);
  const int n0 = nt * 256, m0 = mt * 256;

  const int aoff = (wm * 128 + fr5) * 64 + (((h << 1) ^ chunk_key(fr5)) << 4);

  const unsigned char* Bb = TfT + ((size_t)(m0 + wn * 64 + fr5)) * 64 + h * 32;
#define BK_T(kt) (Bb + (size_t)(kt) * (M_PTS * 64))

  unsigned char* B0 = lds8;
  unsigned char* B1 = lds8 + 16384;
  unsigned char* B2 = lds8 + 32768;

  stgA(Xf, n0, 0, B0, tid);       stgA(Xf, n0 + 128, 0, B0 + 8192, tid);
  stgA(Xf, n0, 64, B1, tid);      stgA(Xf, n0 + 128, 64, B1 + 8192, tid);
  asm volatile("s_waitcnt vmcnt(0)" ::: "memory");
  BARRIER;

  i32x8 fbA[2], fbB[2];
  fbA[0] = ld2x16(BK_T(0), BK_T(0) + 16);
  fbA[1] = ld2x16(BK_T(0) + 2048, BK_T(0) + 2048 + 16);

  f32x16 acc[4][2] = {};
  ktile<6, true, true, true>(B0, B2, Xf, BK_T(1), n0, 128, tid, aoff, fbA, fbB, acc);  // t0
  ktile<6, true, true, true>(B1, B0, Xf, BK_T(2), n0, 192, tid, aoff, fbB, fbA, acc);  // t1
  ktile<6, true, true, true>(B2, B1, Xf, BK_T(3), n0, 256, tid, aoff, fbA, fbB, acc);  // t2
  ktile<6, true, true, true>(B0, B2, Xf, BK_T(4), n0, 320, tid, aoff, fbB, fbA, acc);  // t3
  ktile<6, true, true, true>(B1, B0, Xf, BK_T(5), n0, 384, tid, aoff, fbA, fbB, acc);  // t4
  ktile<6, true, true, true>(B2, B1, Xf, BK_T(6), n0, 448, tid, aoff, fbB, fbA, acc);  // t5
  ktile<4, false, true, true>(B0, B2, Xf, BK_T(7), n0, 0, tid, aoff, fbA, fbB, acc);   // t6
  ktile<-1, false, false, false>(B1, B2, Xf, BK_T(7), n0, 0, tid, aoff, fbB, fbA, acc); // t7

  // Epilogue: v = phi_b[n] - dot; min over the wave's 128 rows per column.
  // 32x32 C/D layout (m74/m101): col = lane&31, row = (q&3)+8*(q>>2)+4*h
  float mv0 = 3.4e38f, mv1 = 3.4e38f;
#pragma unroll
  for (int i = 0; i < 4; ++i) {
    float pb[16];
#pragma unroll
    for (int q = 0; q < 16; ++q)
      pb[q] = phi_b[n0 + wm * 128 + i * 32 + (q & 3) + 8 * (q >> 2) + 4 * h];
#pragma unroll
    for (int q = 0; q < 16; ++q) {
      mv0 = fminf(mv0, pb[q] - acc[i][0][q]);
      mv1 = fminf(mv1, pb[q] - acc[i][1][q]);
    }
  }
  mv0 = fminf(mv0, __shfl_xor(mv0, 32));
  mv1 = fminf(mv1, __shfl_xor(mv1, 32));
  if (h == 0) {
    atomicMin(&keys[m0 + wn * 64 + fr5], fenc(mv0));
    atomicMin(&keys[m0 + wn * 64 + 32 + fr5], fenc(mv1));
  }
#undef BK_T
}

// =====================================================================
// Kernel 4: partial reduce — 64 blocks x 256 threads (unchanged).
// =====================================================================
__global__ __launch_bounds__(256)
void partial_kernel(const float* __restrict__ xsq, const float* __restrict__ phi_b,
                    const float* __restrict__ tsq, const unsigned* __restrict__ keys,
                    double* __restrict__ partials) {
  const int b = blockIdx.x, t = threadIdx.x;
  double s;
  if (b < 32) {
    const int n = b * 256 + t;
    s = 0.5 * (double)xsq[n] - (double)phi_b[n];
  } else {
    const int m = (b - 32) * 256 + t;
    s = 0.5 * (double)tsq[m] + (double)fdec(keys[m]);
  }
  const int lane = t & 63, wv = t >> 6;
#pragma unroll
  for (int k = 1; k <= 32; k <<= 1) s += __shfl_xor(s, k);
  __shared__ double ps[4];
  if (lane == 0) ps[wv] = s;
  __syncthreads();
  if (t == 0) partials[b] = ps[0] + ps[1] + ps[2] + ps[3];
}

// =====================================================================
// Kernel 5: final: sum 64 partials (fixed order), write scalar.
// =====================================================================
__global__ __launch_bounds__(64)
void final_kernel(const double* __restrict__ partials, float* __restrict__ out) {
  if (threadIdx.x == 0) {
    double a = 0.0, c = 0.0;
#pragma unroll
    for (int i = 0; i < 32; ++i) a += partials[i];
#pragma unroll
    for (int i = 32; i < 64; ++i) c += partials[i];
    out[0] = (float)(a / N_PTS + c / M_PTS);
  }
}

// =====================================================================
extern "C" void kernel_launch(void* const* d_in, const int* in_sizes, int n_in,
                              void* d_out, int out_size, void* d_ws, size_t ws_size,
                              hipStream_t stream) {
  const float* x = (const float*)d_in[0];
  const float* tgt = (const float*)d_in[1];
  const float* W = (const float*)d_in[2];

  char* ws = (char*)d_ws;
  const size_t XB_BYTES = (size_t)N_PTS * DIM * 2;   // bf16 x (for phi_b)
  const size_t XF_BYTES = (size_t)N_PTS * DIM;       // fp8 x (plain row order)
  const size_t TF_BYTES = (size_t)M_PTS * DIM;       // fp8 t (fragment-major)
  const size_t WT_BYTES = (size_t)KDIM * DIM * 2;
  unsigned short* Xb = (unsigned short*)ws;
  unsigned char* Xf8 = (unsigned char*)(ws + XB_BYTES);
  unsigned char* TfT = (unsigned char*)(ws + XB_BYTES + XF_BYTES);
  unsigned short* WbT = (unsigned short*)(ws + XB_BYTES + XF_BYTES + TF_BYTES);
  float* phi_b = (float*)(ws + XB_BYTES + XF_BYTES + TF_BYTES + WT_BYTES);
  float* xsq = phi_b + N_PTS;
  float* tsq = xsq + N_PTS;
  unsigned* keys = (unsigned*)(tsq + M_PTS);
  double* partials = (double*)(keys + M_PTS + 64);   // 8B-aligned region

  const int prep_blocks = (N_PTS + M_PTS) / 4 + (KDIM * DIM) / 256;
  prep_all_kernel<<<prep_blocks, 256, 0, stream>>>(x, tgt, W, Xb, Xf8, TfT, WbT,
                                                   xsq, tsq, keys);
  phi_b_kernel<<<N_PTS / 32, 256, 0, stream>>>((const short*)Xb, (const short*)WbT, phi_b);
  gemm_min_kernel<<<(N_PTS / 256) * (M_PTS / 256), 512, 0, stream>>>(Xf8, TfT, phi_b, keys);
  partial_kernel<<<64, 256, 0, stream>>>(xsq, phi_b, tsq, keys, partials);
  final_kernel<<<1, 64, 0, stream>>>(partials, (float*)d_out);
}